// Round 1
// baseline (317.856 us; speedup 1.0000x reference)
//
#include <hip/hip_runtime.h>

// Problem constants
#define NEXP   8
#define L1DIM  3072
#define BATCH  32768
#define SQCORR (127.0f / 128.0f)

// Workspace layout (int units)
#define WS_COUNTS   0        // [8]
#define WS_CURSORS  8        // [8]
#define WS_BLKEXP   24       // [NBLK_MAIN]
#define NBLK_MAIN   2056     // ceil((32768 + 8*15)/16)
#define WS_SORTED   2304     // [SORTED_LEN]
#define SORTED_LEN  (BATCH + NEXP * 16)

__global__ void zero_counts_k(int* ws) {
    if (threadIdx.x < NEXP) ws[WS_COUNTS + threadIdx.x] = 0;
}

// Wave-aggregated histogram: 8 atomics per wave max.
__global__ void hist_k(const int* __restrict__ routing, int* ws) {
    int lane = threadIdx.x & 63;
    int i = blockIdx.x * blockDim.x + threadIdx.x;
    int stride = gridDim.x * blockDim.x;
    for (; i < BATCH; i += stride) {
        int my_e = routing[i];
        #pragma unroll
        for (int e = 0; e < NEXP; ++e) {
            unsigned long long m = __ballot(my_e == e);
            if (m) {
                int leader = __ffsll((long long)m) - 1;
                if (lane == leader) atomicAdd(&ws[WS_COUNTS + e], __popcll(m));
            }
        }
    }
}

// Single thread: aligned segment offsets -> cursors; per-block expert map.
__global__ void scan_k(int* ws) {
    int off = 0;
    for (int e = 0; e < NEXP; ++e) {
        int c = ws[WS_COUNTS + e];
        ws[WS_CURSORS + e] = off;
        int nb = (c + 15) >> 4;
        int b0 = off >> 4;
        for (int b = 0; b < nb; ++b) ws[WS_BLKEXP + b0 + b] = e;
        off += nb << 4;
    }
    for (int b = off >> 4; b < NBLK_MAIN; ++b) ws[WS_BLKEXP + b] = 0;
}

// Wave-aggregated scatter of row indices into expert segments.
__global__ void scatter_k(const int* __restrict__ routing, int* ws) {
    int lane = threadIdx.x & 63;
    int i = blockIdx.x * blockDim.x + threadIdx.x;
    int stride = gridDim.x * blockDim.x;
    for (; i < BATCH; i += stride) {
        int my_e = routing[i];
        #pragma unroll
        for (int e = 0; e < NEXP; ++e) {
            unsigned long long m = __ballot(my_e == e);
            if (m) {
                int leader = __ffsll((long long)m) - 1;
                int base = 0;
                if (lane == leader) base = atomicAdd(&ws[WS_CURSORS + e], __popcll(m));
                base = __shfl(base, leader, 64);
                if (my_e == e) {
                    int rank = (int)__popcll(m & ((1ULL << lane) - 1ULL));
                    ws[WS_SORTED + base + rank] = i;
                }
            }
        }
    }
}

// Main fused kernel: block = 256 threads (4 waves), 16 rows/block (4 rows/wave),
// all rows in a block belong to one expert (segments padded to 16 with -1).
__global__ __launch_bounds__(256) void moe_main_k(
        const float* __restrict__ x, const int* __restrict__ ws,
        const float* __restrict__ w1, const float* __restrict__ b1,
        const float* __restrict__ w2, const float* __restrict__ b2,
        const float* __restrict__ w3, const float* __restrict__ b3,
        float* __restrict__ out) {
    const int wid  = threadIdx.x >> 6;
    const int lane = threadIdx.x & 63;
    const int e    = ws[WS_BLKEXP + blockIdx.x];
    const int slot = blockIdx.x * 16 + wid * 4;

    int rows[4];
    const float* xp[4];
    #pragma unroll
    for (int q = 0; q < 4; ++q) {
        rows[q] = ws[WS_SORTED + slot + q];
        int r = rows[q] < 0 ? 0 : rows[q];
        xp[q] = x + (size_t)r * L1DIM;
    }
    const float* w1e = w1 + (size_t)e * 16 * L1DIM;

    // v[q*16+o] = partial dot of row q against w1[e][o]
    float v[64];
    #pragma unroll
    for (int k = 0; k < 64; ++k) v[k] = 0.0f;

    #pragma unroll 2
    for (int it = 0; it < L1DIM / 256; ++it) {   // 12 iterations
        const int i = it * 256 + lane * 4;
        float4 xv[4];
        #pragma unroll
        for (int q = 0; q < 4; ++q) xv[q] = *(const float4*)(xp[q] + i);
        const float* wp = w1e + i;
        #pragma unroll
        for (int o = 0; o < 16; ++o) {
            float4 wv = *(const float4*)(wp + o * L1DIM);
            #pragma unroll
            for (int q = 0; q < 4; ++q) {
                float s = v[q * 16 + o];
                s = fmaf(xv[q].x, wv.x, s);
                s = fmaf(xv[q].y, wv.y, s);
                s = fmaf(xv[q].z, wv.z, s);
                s = fmaf(xv[q].w, wv.w, s);
                v[q * 16 + o] = s;
            }
        }
    }

    // Reduce-scatter butterfly over 64 lanes: lane l ends with total of idx l.
    #pragma unroll
    for (int s = 0; s < 6; ++s) {
        const int mask = 32 >> s;     // also the half-size at this stage
        const bool hi = (lane & mask) != 0;
        #pragma unroll
        for (int k = 0; k < 32; ++k) {
            if (k >= mask) break;     // keeps indices compile-time after unroll
            float give = hi ? v[k] : v[k + mask];
            float got  = __shfl_xor(give, mask, 64);
            float keep = hi ? v[k + mask] : v[k];
            v[k] = keep + got;
        }
    }

    __shared__ float tot[4][64];
    tot[wid][lane] = v[0];
    __syncthreads();

    // Epilogue: 16 lanes per row. lane = q*16 + j
    const int q = lane >> 4;
    const int j = lane & 15;
    const int row = rows[q];

    const float* tq = &tot[wid][q * 16];
    float l1x_out = tq[15] + b1[e * 16 + 15];

    float h1v[30];
    #pragma unroll
    for (int i = 0; i < 15; ++i) {
        float t = tq[i] + b1[e * 16 + i];
        float sq = t * t * SQCORR;
        h1v[i]      = fminf(fmaxf(sq, 0.0f), 1.0f);
        h1v[i + 15] = fminf(fmaxf(t,  0.0f), 1.0f);
    }

    float s0 = b2[e * 32 + j];
    float s1 = b2[e * 32 + 16 + j];
    const float* w2e = w2 + (size_t)e * 32 * 30;
    #pragma unroll
    for (int i = 0; i < 30; ++i) {
        s0 = fmaf(h1v[i], w2e[j * 30 + i], s0);
        s1 = fmaf(h1v[i], w2e[(16 + j) * 30 + i], s1);
    }
    s0 = fminf(fmaxf(s0, 0.0f), 1.0f);
    s1 = fminf(fmaxf(s1, 0.0f), 1.0f);

    float p = s0 * w3[e * 32 + j] + s1 * w3[e * 32 + 16 + j];
    #pragma unroll
    for (int m = 8; m >= 1; m >>= 1) p += __shfl_xor(p, m, 64);

    if (j == 0 && row >= 0) out[row] = p + b3[e] + l1x_out;
}

extern "C" void kernel_launch(void* const* d_in, const int* in_sizes, int n_in,
                              void* d_out, int out_size, void* d_ws, size_t ws_size,
                              hipStream_t stream) {
    const float* x       = (const float*)d_in[0];
    const int*   routing = (const int*)d_in[1];
    const float* w1      = (const float*)d_in[2];
    const float* b1      = (const float*)d_in[3];
    const float* w2      = (const float*)d_in[4];
    const float* b2      = (const float*)d_in[5];
    const float* w3      = (const float*)d_in[6];
    const float* b3      = (const float*)d_in[7];
    float* out = (float*)d_out;
    int*   ws  = (int*)d_ws;

    hipMemsetAsync(ws + WS_SORTED, 0xFF, SORTED_LEN * sizeof(int), stream);
    zero_counts_k<<<1, 64, 0, stream>>>(ws);
    hist_k<<<64, 256, 0, stream>>>(routing, ws);
    scan_k<<<1, 1, 0, stream>>>(ws);
    scatter_k<<<64, 256, 0, stream>>>(routing, ws);
    moe_main_k<<<NBLK_MAIN, 256, 0, stream>>>(x, ws, w1, b1, w2, b2, w3, b3, out);
}

// Round 2
// 224.720 us; speedup vs baseline: 1.4145x; 1.4145x over previous
//
#include <hip/hip_runtime.h>

// Problem constants
#define NEXP   8
#define L1DIM  3072
#define BATCH  32768
#define SQCORR (127.0f / 128.0f)
#define CHUNK  256                    // K-chunk (floats)
#define NCHUNK (L1DIM / CHUNK)        // 12

// Workspace layout (int units)
#define WS_COUNTS   0                 // [8]
#define WS_CURSORS  8                 // [8]
#define WS_SEG      16                // [9] row-unit segment starts (16-aligned)
#define WS_SORTED   32                // [SORTED_LEN]
#define SORTED_LEN  (BATCH + NEXP * 16)   // 32896
#define NBLK_MAIN   (SORTED_LEN / 16)     // 2056

__global__ void zero_counts_k(int* ws) {
    if (threadIdx.x < NEXP) ws[WS_COUNTS + threadIdx.x] = 0;
}

// Wave-aggregated histogram: 8 atomics per wave max.
__global__ void hist_k(const int* __restrict__ routing, int* ws) {
    int lane = threadIdx.x & 63;
    int i = blockIdx.x * blockDim.x + threadIdx.x;
    int stride = gridDim.x * blockDim.x;
    for (; i < BATCH; i += stride) {
        int my_e = routing[i];
        #pragma unroll
        for (int e = 0; e < NEXP; ++e) {
            unsigned long long m = __ballot(my_e == e);
            if (m) {
                int leader = __ffsll((long long)m) - 1;
                if (lane == leader) atomicAdd(&ws[WS_COUNTS + e], __popcll(m));
            }
        }
    }
}

// 1 block / 64 threads: thread 0 does the 8-entry scan; all threads fill the
// (<=248) padding slots with -1. Replaces the old 2056-iteration serial loop
// and the 131KB memset.
__global__ void scan_k(int* ws) {
    __shared__ int seg[NEXP + 1];
    __shared__ int cnt[NEXP];
    if (threadIdx.x == 0) {
        int off = 0;
        for (int e = 0; e < NEXP; ++e) {
            int c = ws[WS_COUNTS + e];
            cnt[e] = c;
            ws[WS_CURSORS + e] = off;
            seg[e] = off;
            ws[WS_SEG + e] = off;
            off += ((c + 15) >> 4) << 4;
        }
        seg[NEXP] = off;
        ws[WS_SEG + NEXP] = off;
    }
    __syncthreads();
    int t = threadIdx.x;
    for (int e = 0; e < NEXP; ++e) {
        int lo = seg[e] + cnt[e], hi = seg[e + 1];
        for (int i = lo + t; i < hi; i += 64) ws[WS_SORTED + i] = -1;
    }
    for (int i = seg[NEXP] + t; i < SORTED_LEN; i += 64) ws[WS_SORTED + i] = -1;
}

// Wave-aggregated scatter of row indices into expert segments.
__global__ void scatter_k(const int* __restrict__ routing, int* ws) {
    int lane = threadIdx.x & 63;
    int i = blockIdx.x * blockDim.x + threadIdx.x;
    int stride = gridDim.x * blockDim.x;
    for (; i < BATCH; i += stride) {
        int my_e = routing[i];
        #pragma unroll
        for (int e = 0; e < NEXP; ++e) {
            unsigned long long m = __ballot(my_e == e);
            if (m) {
                int leader = __ffsll((long long)m) - 1;
                int base = 0;
                if (lane == leader) base = atomicAdd(&ws[WS_CURSORS + e], __popcll(m));
                base = __shfl(base, leader, 64);
                if (my_e == e) {
                    int rank = (int)__popcll(m & ((1ULL << lane) - 1ULL));
                    ws[WS_SORTED + base + rank] = i;
                }
            }
        }
    }
}

// async 16B global -> LDS copy (per-lane global src, wave-linear LDS dest)
__device__ __forceinline__ void lds_cp16(void* lds, const void* g) {
    __builtin_amdgcn_global_load_lds(
        (const __attribute__((address_space(1))) void*)g,
        (__attribute__((address_space(3))) void*)lds, 16, 0, 0);
}

// Main fused kernel: 256 threads (4 waves), 16 rows/block, one expert/block.
// 2-phase async pipeline: stage chunk t+1 (global_load_lds) || compute chunk t.
__global__ __launch_bounds__(256, 2) void moe_main_k(
        const float* __restrict__ x, const int* __restrict__ ws,
        const float* __restrict__ w1, const float* __restrict__ b1,
        const float* __restrict__ w2, const float* __restrict__ b2,
        const float* __restrict__ w3, const float* __restrict__ b3,
        float* __restrict__ out) {
    __shared__ float xs [2][16][CHUNK];   // 32 KB
    __shared__ float w1s[2][16][CHUNK];   // 32 KB
    __shared__ float tot[4][64];          // 1 KB

    const int tid  = threadIdx.x;
    const int wid  = tid >> 6;
    const int lane = tid & 63;
    const int rowbase = blockIdx.x * 16;

    // expert from 9-entry segment table (row units, nondecreasing)
    int e = 0;
    #pragma unroll
    for (int i = 1; i < NEXP; ++i)
        if (rowbase >= ws[WS_SEG + i]) e = i;

    const int slot = rowbase + wid * 4;
    int rows[4];
    const float* xp[4];
    #pragma unroll
    for (int q = 0; q < 4; ++q) {
        rows[q] = ws[WS_SORTED + slot + q];
        int r = rows[q] < 0 ? 0 : rows[q];
        xp[q] = x + (size_t)r * L1DIM;
    }
    const float* w1e = w1 + (size_t)e * 16 * L1DIM;

    float acc[64];
    #pragma unroll
    for (int k = 0; k < 64; ++k) acc[k] = 0.0f;

    const int r0 = wid * 4;

    // ---- stage chunk 0 ----
    {
        const int koff = lane * 4;
        #pragma unroll
        for (int q = 0; q < 4; ++q) {
            lds_cp16(&xs [0][r0 + q][lane * 4], xp[q] + koff);
            lds_cp16(&w1s[0][r0 + q][lane * 4], w1e + (size_t)(r0 + q) * L1DIM + koff);
        }
    }
    __syncthreads();   // drains vmcnt -> chunk 0 resident

    int buf = 0;
    for (int t = 0; t < NCHUNK; ++t) {
        // issue next chunk's async loads first (overlap with compute below)
        if (t + 1 < NCHUNK) {
            const int koff = (t + 1) * CHUNK + lane * 4;
            #pragma unroll
            for (int q = 0; q < 4; ++q) {
                lds_cp16(&xs [buf ^ 1][r0 + q][lane * 4], xp[q] + koff);
                lds_cp16(&w1s[buf ^ 1][r0 + q][lane * 4], w1e + (size_t)(r0 + q) * L1DIM + koff);
            }
        }
        // compute chunk t from LDS
        float4 xv[4];
        #pragma unroll
        for (int q = 0; q < 4; ++q)
            xv[q] = *(const float4*)&xs[buf][r0 + q][lane * 4];
        #pragma unroll
        for (int o = 0; o < 16; ++o) {
            float4 wv = *(const float4*)&w1s[buf][o][lane * 4];
            #pragma unroll
            for (int q = 0; q < 4; ++q) {
                float s = acc[q * 16 + o];
                s = fmaf(xv[q].x, wv.x, s);
                s = fmaf(xv[q].y, wv.y, s);
                s = fmaf(xv[q].z, wv.z, s);
                s = fmaf(xv[q].w, wv.w, s);
                acc[q * 16 + o] = s;
            }
        }
        __syncthreads();   // drains vmcnt+lgkmcnt: next chunk resident, buf free
        buf ^= 1;
    }

    // Reduce-scatter butterfly over 64 lanes: lane l ends with total of idx l.
    #pragma unroll
    for (int s = 0; s < 6; ++s) {
        const int mask = 32 >> s;
        const bool hi = (lane & mask) != 0;
        #pragma unroll
        for (int k = 0; k < 32; ++k) {
            if (k >= mask) break;
            float give = hi ? acc[k] : acc[k + mask];
            float got  = __shfl_xor(give, mask, 64);
            float keep = hi ? acc[k + mask] : acc[k];
            acc[k] = keep + got;
        }
    }

    tot[wid][lane] = acc[0];
    __syncthreads();

    // Epilogue: 16 lanes per row. lane = q*16 + j
    const int q = lane >> 4;
    const int j = lane & 15;
    const int row = rows[q];

    const float* tq = &tot[wid][q * 16];
    float l1x_out = tq[15] + b1[e * 16 + 15];

    float h1v[30];
    #pragma unroll
    for (int i = 0; i < 15; ++i) {
        float t = tq[i] + b1[e * 16 + i];
        float sq = t * t * SQCORR;
        h1v[i]      = fminf(fmaxf(sq, 0.0f), 1.0f);
        h1v[i + 15] = fminf(fmaxf(t,  0.0f), 1.0f);
    }

    float s0 = b2[e * 32 + j];
    float s1 = b2[e * 32 + 16 + j];
    const float* w2e = w2 + (size_t)e * 32 * 30;
    #pragma unroll
    for (int i = 0; i < 30; ++i) {
        s0 = fmaf(h1v[i], w2e[j * 30 + i], s0);
        s1 = fmaf(h1v[i], w2e[(16 + j) * 30 + i], s1);
    }
    s0 = fminf(fmaxf(s0, 0.0f), 1.0f);
    s1 = fminf(fmaxf(s1, 0.0f), 1.0f);

    float p = s0 * w3[e * 32 + j] + s1 * w3[e * 32 + 16 + j];
    #pragma unroll
    for (int m = 8; m >= 1; m >>= 1) p += __shfl_xor(p, m, 64);

    if (j == 0 && row >= 0) out[row] = p + b3[e] + l1x_out;
}

extern "C" void kernel_launch(void* const* d_in, const int* in_sizes, int n_in,
                              void* d_out, int out_size, void* d_ws, size_t ws_size,
                              hipStream_t stream) {
    const float* x       = (const float*)d_in[0];
    const int*   routing = (const int*)d_in[1];
    const float* w1      = (const float*)d_in[2];
    const float* b1      = (const float*)d_in[3];
    const float* w2      = (const float*)d_in[4];
    const float* b2      = (const float*)d_in[5];
    const float* w3      = (const float*)d_in[6];
    const float* b3      = (const float*)d_in[7];
    float* out = (float*)d_out;
    int*   ws  = (int*)d_ws;

    zero_counts_k<<<1, 64, 0, stream>>>(ws);
    hist_k<<<64, 256, 0, stream>>>(routing, ws);
    scan_k<<<1, 64, 0, stream>>>(ws);
    scatter_k<<<64, 256, 0, stream>>>(routing, ws);
    moe_main_k<<<NBLK_MAIN, 256, 0, stream>>>(x, ws, w1, b1, w2, b2, w3, b3, out);
}

// Round 3
// 141.938 us; speedup vs baseline: 2.2394x; 1.5832x over previous
//
#include <hip/hip_runtime.h>

// Problem constants
#define NEXP   8
#define L1DIM  3072
#define BATCH  32768
#define SQCORR (127.0f / 128.0f)
#define CHUNK  256                    // K-chunk (floats)
#define NCHUNK (L1DIM / CHUNK)        // 12

// Workspace layout (int units)
#define WS_COUNTS   0                 // [8]
#define WS_CURSORS  8                 // [8]
#define WS_SEG      16                // [9] row-unit segment starts (16-aligned)
#define WS_SORTED   32                // [SORTED_LEN]
#define SORTED_LEN  (BATCH + NEXP * 16)   // 32896
#define NBLK_MAIN   (SORTED_LEN / 16)     // 2056
#define NBLK_SORT   (BATCH / 256)         // 128 (exact: 128*256 = 32768)

__global__ void zero_counts_k(int* ws) {
    if (threadIdx.x < NEXP) ws[WS_COUNTS + threadIdx.x] = 0;
}

// Block-aggregated histogram: LDS atomics, then 8 global atomics per block.
__global__ void hist_k(const int* __restrict__ routing, int* ws) {
    __shared__ int h[NEXP];
    if (threadIdx.x < NEXP) h[threadIdx.x] = 0;
    __syncthreads();
    int i = blockIdx.x * 256 + threadIdx.x;
    atomicAdd(&h[routing[i]], 1);
    __syncthreads();
    if (threadIdx.x < NEXP) atomicAdd(&ws[WS_COUNTS + threadIdx.x], h[threadIdx.x]);
}

// 1 block / 64 threads: thread 0 does the 8-entry scan; all threads fill the
// (<=248) padding slots with -1.
__global__ void scan_k(int* ws) {
    __shared__ int seg[NEXP + 1];
    __shared__ int cnt[NEXP];
    if (threadIdx.x == 0) {
        int off = 0;
        for (int e = 0; e < NEXP; ++e) {
            int c = ws[WS_COUNTS + e];
            cnt[e] = c;
            ws[WS_CURSORS + e] = off;
            seg[e] = off;
            ws[WS_SEG + e] = off;
            off += ((c + 15) >> 4) << 4;
        }
        seg[NEXP] = off;
        ws[WS_SEG + NEXP] = off;
    }
    __syncthreads();
    int t = threadIdx.x;
    for (int e = 0; e < NEXP; ++e) {
        int lo = seg[e] + cnt[e], hi = seg[e + 1];
        for (int i = lo + t; i < hi; i += 64) ws[WS_SORTED + i] = -1;
    }
    for (int i = seg[NEXP] + t; i < SORTED_LEN; i += 64) ws[WS_SORTED + i] = -1;
}

// Block-aggregated scatter: LDS ranks + 8 global atomics per block.
// Order within an expert segment is arbitrary (per-row math is placement-
// invariant, so output remains deterministic).
__global__ void scatter_k(const int* __restrict__ routing, int* ws) {
    __shared__ int h[NEXP];
    __shared__ int base[NEXP];
    if (threadIdx.x < NEXP) h[threadIdx.x] = 0;
    __syncthreads();
    int i = blockIdx.x * 256 + threadIdx.x;
    int e = routing[i];
    int rank = atomicAdd(&h[e], 1);
    __syncthreads();
    if (threadIdx.x < NEXP)
        base[threadIdx.x] = atomicAdd(&ws[WS_CURSORS + threadIdx.x], h[threadIdx.x]);
    __syncthreads();
    ws[WS_SORTED + base[e] + rank] = i;
}

// async 16B global -> LDS copy (per-lane global src, wave-linear LDS dest)
__device__ __forceinline__ void lds_cp16(void* lds, const void* g) {
    __builtin_amdgcn_global_load_lds(
        (const __attribute__((address_space(1))) void*)g,
        (__attribute__((address_space(3))) void*)lds, 16, 0, 0);
}

// Main fused kernel: 256 threads (4 waves), 16 rows/block, one expert/block.
// 3-deep x pipeline + 2-deep w1 pipeline with counted vmcnt (T3/T4):
//   prologue: issue w1(0), x(0), x(1)
//   iter t:   s_waitcnt vmcnt(4); s_barrier;        // x(t), w1(t) resident
//             issue w1(t+1), x(t+2); compute(t)
// FIFO at each wait: [x(t), w1(t), x(t+1)] -> allow 4 newest = x(t+1).
__global__ __launch_bounds__(256, 2) void moe_main_k(
        const float* __restrict__ x, const int* __restrict__ ws,
        const float* __restrict__ w1, const float* __restrict__ b1,
        const float* __restrict__ w2, const float* __restrict__ b2,
        const float* __restrict__ w3, const float* __restrict__ b3,
        float* __restrict__ out) {
    __shared__ float xs [3][16][CHUNK];   // 48 KB
    __shared__ float w1s[2][16][CHUNK];   // 32 KB  (total exactly 80 KB -> 2 blk/CU)

    const int tid  = threadIdx.x;
    const int wid  = tid >> 6;
    const int lane = tid & 63;
    const int rowbase = blockIdx.x * 16;

    // expert from 9-entry segment table (row units, nondecreasing)
    int e = 0;
    #pragma unroll
    for (int i = 1; i < NEXP; ++i)
        if (rowbase >= ws[WS_SEG + i]) e = i;

    const int slot = rowbase + wid * 4;
    int rows[4];
    const float* xp[4];
    #pragma unroll
    for (int q = 0; q < 4; ++q) {
        rows[q] = ws[WS_SORTED + slot + q];
        int r = rows[q] < 0 ? 0 : rows[q];
        xp[q] = x + (size_t)r * L1DIM;
    }
    const float* w1e = w1 + (size_t)e * 16 * L1DIM;
    const int r0   = wid * 4;
    const int loff = lane * 4;

    auto issue_w1 = [&](int t, int b) {
        const int koff = t * CHUNK + loff;
        #pragma unroll
        for (int q = 0; q < 4; ++q)
            lds_cp16(&w1s[b][r0 + q][loff], w1e + (size_t)(r0 + q) * L1DIM + koff);
    };
    auto issue_x = [&](int t, int b) {
        const int koff = t * CHUNK + loff;
        #pragma unroll
        for (int q = 0; q < 4; ++q)
            lds_cp16(&xs[b][r0 + q][loff], xp[q] + koff);
    };

    float acc[64];
    #pragma unroll
    for (int k = 0; k < 64; ++k) acc[k] = 0.0f;

    // prologue (issue order matters for vmcnt bookkeeping: w1 first)
    issue_w1(0, 0);
    issue_x(0, 0);
    issue_x(1, 1);

    int xb = 0, wb = 0;
    #pragma unroll 1
    for (int t = 0; t < NCHUNK - 1; ++t) {
        asm volatile("s_waitcnt vmcnt(4)" ::: "memory");
        __builtin_amdgcn_s_barrier();
        __builtin_amdgcn_sched_barrier(0);
        // prefetch (after barrier: recycled buffers are free block-wide)
        issue_w1(t + 1, wb ^ 1);
        if (t + 2 < NCHUNK) issue_x(t + 2, (xb + 2) % 3);
        // compute chunk t from LDS
        float4 xv[4];
        #pragma unroll
        for (int q = 0; q < 4; ++q)
            xv[q] = *(const float4*)&xs[xb][r0 + q][loff];
        #pragma unroll
        for (int o = 0; o < 16; ++o) {
            float4 wv = *(const float4*)&w1s[wb][o][loff];
            #pragma unroll
            for (int q = 0; q < 4; ++q) {
                float s = acc[q * 16 + o];
                s = fmaf(xv[q].x, wv.x, s);
                s = fmaf(xv[q].y, wv.y, s);
                s = fmaf(xv[q].z, wv.z, s);
                s = fmaf(xv[q].w, wv.w, s);
                acc[q * 16 + o] = s;
            }
        }
        xb = (xb + 1) % 3;
        wb ^= 1;
    }
    // last chunk (t = NCHUNK-1): drain
    asm volatile("s_waitcnt vmcnt(0)" ::: "memory");
    __builtin_amdgcn_s_barrier();
    __builtin_amdgcn_sched_barrier(0);
    {
        float4 xv[4];
        #pragma unroll
        for (int q = 0; q < 4; ++q)
            xv[q] = *(const float4*)&xs[xb][r0 + q][loff];
        #pragma unroll
        for (int o = 0; o < 16; ++o) {
            float4 wv = *(const float4*)&w1s[wb][o][loff];
            #pragma unroll
            for (int q = 0; q < 4; ++q) {
                float s = acc[q * 16 + o];
                s = fmaf(xv[q].x, wv.x, s);
                s = fmaf(xv[q].y, wv.y, s);
                s = fmaf(xv[q].z, wv.z, s);
                s = fmaf(xv[q].w, wv.w, s);
                acc[q * 16 + o] = s;
            }
        }
    }

    // Reduce-scatter butterfly over 64 lanes: lane l ends with total of idx l.
    #pragma unroll
    for (int s = 0; s < 6; ++s) {
        const int mask = 32 >> s;
        const bool hi = (lane & mask) != 0;
        #pragma unroll
        for (int k = 0; k < 32; ++k) {
            if (k >= mask) break;
            float give = hi ? acc[k] : acc[k + mask];
            float got  = __shfl_xor(give, mask, 64);
            float keep = hi ? acc[k + mask] : acc[k];
            acc[k] = keep + got;
        }
    }

    __syncthreads();                       // everyone done with w1s
    float* tot = &w1s[0][0][0];            // alias 1 KB of w1s for totals
    tot[wid * 64 + lane] = acc[0];
    __syncthreads();

    // Epilogue: 16 lanes per row. lane = q*16 + j
    const int q = lane >> 4;
    const int j = lane & 15;
    const int row = rows[q];

    const float* tq = &tot[wid * 64 + q * 16];
    float l1x_out = tq[15] + b1[e * 16 + 15];

    float h1v[30];
    #pragma unroll
    for (int i = 0; i < 15; ++i) {
        float t = tq[i] + b1[e * 16 + i];
        float sq = t * t * SQCORR;
        h1v[i]      = fminf(fmaxf(sq, 0.0f), 1.0f);
        h1v[i + 15] = fminf(fmaxf(t,  0.0f), 1.0f);
    }

    float s0 = b2[e * 32 + j];
    float s1 = b2[e * 32 + 16 + j];
    const float* w2e = w2 + (size_t)e * 32 * 30;
    #pragma unroll
    for (int i = 0; i < 30; ++i) {
        s0 = fmaf(h1v[i], w2e[j * 30 + i], s0);
        s1 = fmaf(h1v[i], w2e[(16 + j) * 30 + i], s1);
    }
    s0 = fminf(fmaxf(s0, 0.0f), 1.0f);
    s1 = fminf(fmaxf(s1, 0.0f), 1.0f);

    float p = s0 * w3[e * 32 + j] + s1 * w3[e * 32 + 16 + j];
    #pragma unroll
    for (int m = 8; m >= 1; m >>= 1) p += __shfl_xor(p, m, 64);

    if (j == 0 && row >= 0) out[row] = p + b3[e] + l1x_out;
}

extern "C" void kernel_launch(void* const* d_in, const int* in_sizes, int n_in,
                              void* d_out, int out_size, void* d_ws, size_t ws_size,
                              hipStream_t stream) {
    const float* x       = (const float*)d_in[0];
    const int*   routing = (const int*)d_in[1];
    const float* w1      = (const float*)d_in[2];
    const float* b1      = (const float*)d_in[3];
    const float* w2      = (const float*)d_in[4];
    const float* b2      = (const float*)d_in[5];
    const float* w3      = (const float*)d_in[6];
    const float* b3      = (const float*)d_in[7];
    float* out = (float*)d_out;
    int*   ws  = (int*)d_ws;

    zero_counts_k<<<1, 64, 0, stream>>>(ws);
    hist_k<<<NBLK_SORT, 256, 0, stream>>>(routing, ws);
    scan_k<<<1, 64, 0, stream>>>(ws);
    scatter_k<<<NBLK_SORT, 256, 0, stream>>>(routing, ws);
    moe_main_k<<<NBLK_MAIN, 256, 0, stream>>>(x, ws, w1, b1, w2, b2, w3, b3, out);
}

// Round 4
// 140.575 us; speedup vs baseline: 2.2611x; 1.0097x over previous
//
#include <hip/hip_runtime.h>

// Problem constants
#define NEXP   8
#define L1DIM  3072
#define BATCH  32768
#define SQCORR (127.0f / 128.0f)
#define CHUNK  256                    // K-chunk (floats)
#define NCHUNK (L1DIM / CHUNK)        // 12

// Workspace layout (int units). Fixed per-expert segments: expert e owns
// sorted slots [e*BATCH, e*BATCH + count_e). No hist/scan/fill needed.
#define WS_CURSORS  0                 // [8] init to e*BATCH; final = base+count
#define WS_SORTED   8                 // [NEXP*BATCH]
#define NBLK_SORT   (BATCH / 256)     // 128
#define BLK_PER_E   (BATCH / 16)      // 2048
#define NBLK_MAIN   (NEXP * BLK_PER_E)// 16384 (most early-exit)

__global__ void init_k(int* ws) {
    if (threadIdx.x < NEXP) ws[WS_CURSORS + threadIdx.x] = threadIdx.x * BATCH;
}

// Block-aggregated scatter into fixed expert segments: LDS ranks + 8 global
// atomics per block. Order within a segment is arbitrary (per-row math is
// placement-invariant, so output stays deterministic).
__global__ void scatter_k(const int* __restrict__ routing, int* ws) {
    __shared__ int h[NEXP];
    __shared__ int base[NEXP];
    if (threadIdx.x < NEXP) h[threadIdx.x] = 0;
    __syncthreads();
    int i = blockIdx.x * 256 + threadIdx.x;
    int e = routing[i];
    int rank = atomicAdd(&h[e], 1);
    __syncthreads();
    if (threadIdx.x < NEXP)
        base[threadIdx.x] = atomicAdd(&ws[WS_CURSORS + threadIdx.x], h[threadIdx.x]);
    __syncthreads();
    ws[WS_SORTED + base[e] + rank] = i;   // base is absolute (includes e*BATCH)
}

// async 16B global -> LDS copy (per-lane global src, wave-linear LDS dest)
__device__ __forceinline__ void lds_cp16(void* lds, const void* g) {
    __builtin_amdgcn_global_load_lds(
        (const __attribute__((address_space(1))) void*)g,
        (__attribute__((address_space(3))) void*)lds, 16, 0, 0);
}

// Main fused kernel: 256 threads (4 waves), 16 rows/block, one expert/block.
// x: 3-deep LDS pipeline via global_load_lds, issue distance 2 chunks.
// w1: direct L2->VGPR float4 loads, 4 outputs at a time (16 wv VGPRs live).
// LDS = 48 KB -> 3 blocks/CU (12 waves/CU).
// vmcnt discipline: all 16 wv loads of chunk t are issued BEFORE the gll
// prefetch of x(t+2) (pinned with sched_barrier), so compiler wv-waits are
// vmcnt(4) and never drain the in-flight x prefetch.
__global__ __launch_bounds__(256, 3) void moe_main_k(
        const float* __restrict__ x, const int* __restrict__ ws,
        const float* __restrict__ w1, const float* __restrict__ b1,
        const float* __restrict__ w2, const float* __restrict__ b2,
        const float* __restrict__ w3, const float* __restrict__ b3,
        float* __restrict__ out) {
    __shared__ float xs[3][16][CHUNK];    // 48 KB
    __shared__ float tot[4][64];          // 1 KB

    const int e   = blockIdx.x / BLK_PER_E;
    const int b16 = (blockIdx.x % BLK_PER_E) * 16;
    const int n   = ws[WS_CURSORS + e] - e * BATCH;   // count_e (post-scatter)
    if (b16 >= n) return;

    const int tid  = threadIdx.x;
    const int wid  = tid >> 6;
    const int lane = tid & 63;
    const int r0   = wid * 4;
    const int loff = lane * 4;

    int rows[4];
    const float* xp[4];
    #pragma unroll
    for (int q = 0; q < 4; ++q) {
        int s = b16 + r0 + q;
        rows[q] = (s < n) ? ws[WS_SORTED + e * BATCH + s] : -1;
        int r = rows[q] < 0 ? 0 : rows[q];
        xp[q] = x + (size_t)r * L1DIM;
    }
    const float* w1e = w1 + (size_t)e * 16 * L1DIM;

    auto issue_x = [&](int t, int b) {
        const int koff = t * CHUNK + loff;
        #pragma unroll
        for (int q = 0; q < 4; ++q)
            lds_cp16(&xs[b][r0 + q][loff], xp[q] + koff);
    };

    float acc[64];
    #pragma unroll
    for (int k = 0; k < 64; ++k) acc[k] = 0.0f;

    // prologue: x(0), x(1) in flight
    issue_x(0, 0);
    issue_x(1, 1);

    #pragma unroll 1
    for (int t = 0; t < NCHUNK - 1; ++t) {
        const int xb = t % 3;
        asm volatile("s_waitcnt vmcnt(4)" ::: "memory");   // x(t) resident
        __builtin_amdgcn_s_barrier();
        __builtin_amdgcn_sched_barrier(0);

        float4 xv[4];
        #pragma unroll
        for (int q = 0; q < 4; ++q)
            xv[q] = *(const float4*)&xs[xb][r0 + q][loff];

        const float* wc = w1e + t * CHUNK + loff;
        #pragma unroll
        for (int g = 0; g < 4; ++g) {
            float4 wv[4];
            #pragma unroll
            for (int oo = 0; oo < 4; ++oo)
                wv[oo] = *(const float4*)(wc + (size_t)(g * 4 + oo) * L1DIM);
            if (g == 3) {
                // all wv of this chunk issued; now the x prefetch is newest
                __builtin_amdgcn_sched_barrier(0);
                if (t + 2 < NCHUNK) issue_x(t + 2, (t + 2) % 3);
                __builtin_amdgcn_sched_barrier(0);
            }
            #pragma unroll
            for (int oo = 0; oo < 4; ++oo) {
                const int o = g * 4 + oo;
                #pragma unroll
                for (int q = 0; q < 4; ++q) {
                    float s = acc[q * 16 + o];
                    s = fmaf(xv[q].x, wv[oo].x, s);
                    s = fmaf(xv[q].y, wv[oo].y, s);
                    s = fmaf(xv[q].z, wv[oo].z, s);
                    s = fmaf(xv[q].w, wv[oo].w, s);
                    acc[q * 16 + o] = s;
                }
            }
        }
        __builtin_amdgcn_s_barrier();   // buffer xb free for reuse next cycle
    }

    // last chunk: drain
    {
        const int t = NCHUNK - 1;
        const int xb = t % 3;
        asm volatile("s_waitcnt vmcnt(0)" ::: "memory");
        __builtin_amdgcn_s_barrier();
        __builtin_amdgcn_sched_barrier(0);
        float4 xv[4];
        #pragma unroll
        for (int q = 0; q < 4; ++q)
            xv[q] = *(const float4*)&xs[xb][r0 + q][loff];
        const float* wc = w1e + t * CHUNK + loff;
        #pragma unroll
        for (int g = 0; g < 4; ++g) {
            float4 wv[4];
            #pragma unroll
            for (int oo = 0; oo < 4; ++oo)
                wv[oo] = *(const float4*)(wc + (size_t)(g * 4 + oo) * L1DIM);
            #pragma unroll
            for (int oo = 0; oo < 4; ++oo) {
                const int o = g * 4 + oo;
                #pragma unroll
                for (int q = 0; q < 4; ++q) {
                    float s = acc[q * 16 + o];
                    s = fmaf(xv[q].x, wv[oo].x, s);
                    s = fmaf(xv[q].y, wv[oo].y, s);
                    s = fmaf(xv[q].z, wv[oo].z, s);
                    s = fmaf(xv[q].w, wv[oo].w, s);
                    acc[q * 16 + o] = s;
                }
            }
        }
    }

    // Reduce-scatter butterfly over 64 lanes: lane l ends with total of idx l.
    #pragma unroll
    for (int s = 0; s < 6; ++s) {
        const int mask = 32 >> s;
        const bool hi = (lane & mask) != 0;
        #pragma unroll
        for (int k = 0; k < 32; ++k) {
            if (k >= mask) break;
            float give = hi ? acc[k] : acc[k + mask];
            float got  = __shfl_xor(give, mask, 64);
            float keep = hi ? acc[k + mask] : acc[k];
            acc[k] = keep + got;
        }
    }

    tot[wid][lane] = acc[0];
    __syncthreads();

    // Epilogue: 16 lanes per row. lane = q*16 + j
    const int q = lane >> 4;
    const int j = lane & 15;
    const int row = rows[q];

    const float* tq = &tot[wid][q * 16];
    float l1x_out = tq[15] + b1[e * 16 + 15];

    float h1v[30];
    #pragma unroll
    for (int i = 0; i < 15; ++i) {
        float t = tq[i] + b1[e * 16 + i];
        float sq = t * t * SQCORR;
        h1v[i]      = fminf(fmaxf(sq, 0.0f), 1.0f);
        h1v[i + 15] = fminf(fmaxf(t,  0.0f), 1.0f);
    }

    float s0 = b2[e * 32 + j];
    float s1 = b2[e * 32 + 16 + j];
    const float* w2e = w2 + (size_t)e * 32 * 30;
    #pragma unroll
    for (int i = 0; i < 30; ++i) {
        s0 = fmaf(h1v[i], w2e[j * 30 + i], s0);
        s1 = fmaf(h1v[i], w2e[(16 + j) * 30 + i], s1);
    }
    s0 = fminf(fmaxf(s0, 0.0f), 1.0f);
    s1 = fminf(fmaxf(s1, 0.0f), 1.0f);

    float p = s0 * w3[e * 32 + j] + s1 * w3[e * 32 + 16 + j];
    #pragma unroll
    for (int m = 8; m >= 1; m >>= 1) p += __shfl_xor(p, m, 64);

    if (j == 0 && row >= 0) out[row] = p + b3[e] + l1x_out;
}

extern "C" void kernel_launch(void* const* d_in, const int* in_sizes, int n_in,
                              void* d_out, int out_size, void* d_ws, size_t ws_size,
                              hipStream_t stream) {
    const float* x       = (const float*)d_in[0];
    const int*   routing = (const int*)d_in[1];
    const float* w1      = (const float*)d_in[2];
    const float* b1      = (const float*)d_in[3];
    const float* w2      = (const float*)d_in[4];
    const float* b2      = (const float*)d_in[5];
    const float* w3      = (const float*)d_in[6];
    const float* b3      = (const float*)d_in[7];
    float* out = (float*)d_out;
    int*   ws  = (int*)d_ws;

    init_k<<<1, 64, 0, stream>>>(ws);
    scatter_k<<<NBLK_SORT, 256, 0, stream>>>(routing, ws);
    moe_main_k<<<NBLK_MAIN, 256, 0, stream>>>(x, ws, w1, b1, w2, b2, w3, b3, out);
}

// Round 5
// 138.838 us; speedup vs baseline: 2.2894x; 1.0125x over previous
//
#include <hip/hip_runtime.h>

// Problem constants
#define NEXP   8
#define L1DIM  3072
#define BATCH  32768
#define SQCORR (127.0f / 128.0f)
#define CHUNK  256                    // K-chunk (floats)
#define NCHUNK (L1DIM / CHUNK)        // 12

// Workspace layout (int units). Fixed per-expert segments: expert e owns
// sorted slots [e*BATCH, e*BATCH + count_e). Cursors padded to one cache
// line each (16 ints = 64 B) so per-expert atomics proceed on independent
// lines instead of serializing on one.
#define CUR_STRIDE  16
#define WS_CURSORS  0                       // [8 * CUR_STRIDE]
#define WS_SORTED   (NEXP * CUR_STRIDE)     // [NEXP*BATCH]
#define NBLK_SORT   (BATCH / 256)           // 128
#define BLK_PER_E   (BATCH / 16)            // 2048
#define NBLK_MAIN   (NEXP * BLK_PER_E)      // 16384 (most early-exit)

__global__ void init_k(int* ws) {
    if (threadIdx.x < NEXP)
        ws[WS_CURSORS + threadIdx.x * CUR_STRIDE] = threadIdx.x * BATCH;
}

// Block-aggregated scatter into fixed expert segments: LDS ranks + 8 global
// atomics per block (one per padded cursor line). Order within a segment is
// arbitrary (per-row math is placement-invariant -> deterministic output).
__global__ void scatter_k(const int* __restrict__ routing, int* ws) {
    __shared__ int h[NEXP];
    __shared__ int base[NEXP];
    if (threadIdx.x < NEXP) h[threadIdx.x] = 0;
    __syncthreads();
    int i = blockIdx.x * 256 + threadIdx.x;
    int e = routing[i];
    int rank = atomicAdd(&h[e], 1);
    __syncthreads();
    if (threadIdx.x < NEXP)
        base[threadIdx.x] =
            atomicAdd(&ws[WS_CURSORS + threadIdx.x * CUR_STRIDE], h[threadIdx.x]);
    __syncthreads();
    ws[WS_SORTED + base[e] + rank] = i;   // base is absolute (includes e*BATCH)
}

// async 16B global -> LDS copy (per-lane global src, wave-linear LDS dest)
__device__ __forceinline__ void lds_cp16(void* lds, const void* g) {
    __builtin_amdgcn_global_load_lds(
        (const __attribute__((address_space(1))) void*)g,
        (__attribute__((address_space(3))) void*)lds, 16, 0, 0);
}

// Main fused kernel: 256 threads (4 waves), 16 rows/block, one expert/block.
// x: 3-deep LDS pipeline via global_load_lds, issue distance 2 chunks.
// w1: direct L2->VGPR float4 loads, 4 outputs at a time.
// LDS = 49 KB -> 3 blocks/CU.
// Block mapping: e = blockIdx % NEXP (NOT /BLK_PER_E) so the ~2048 real
// worker blocks are the LOWEST block IDs, interleaved across experts ->
// dispatcher spreads them evenly 3/CU over all 256 CUs instead of clumping
// each expert's workers onto ~85 CUs while the rest idle.
__global__ __launch_bounds__(256, 3) void moe_main_k(
        const float* __restrict__ x, const int* __restrict__ ws,
        const float* __restrict__ w1, const float* __restrict__ b1,
        const float* __restrict__ w2, const float* __restrict__ b2,
        const float* __restrict__ w3, const float* __restrict__ b3,
        float* __restrict__ out) {
    __shared__ float xs[3][16][CHUNK];    // 48 KB
    __shared__ float tot[4][64];          // 1 KB

    const int e   = blockIdx.x % NEXP;
    const int b16 = (blockIdx.x / NEXP) * 16;
    const int n   = ws[WS_CURSORS + e * CUR_STRIDE] - e * BATCH;  // count_e
    if (b16 >= n) return;

    const int tid  = threadIdx.x;
    const int wid  = tid >> 6;
    const int lane = tid & 63;
    const int r0   = wid * 4;
    const int loff = lane * 4;

    int rows[4];
    const float* xp[4];
    #pragma unroll
    for (int q = 0; q < 4; ++q) {
        int s = b16 + r0 + q;
        rows[q] = (s < n) ? ws[WS_SORTED + e * BATCH + s] : -1;
        int r = rows[q] < 0 ? 0 : rows[q];
        xp[q] = x + (size_t)r * L1DIM;
    }
    const float* w1e = w1 + (size_t)e * 16 * L1DIM;

    auto issue_x = [&](int t, int b) {
        const int koff = t * CHUNK + loff;
        #pragma unroll
        for (int q = 0; q < 4; ++q)
            lds_cp16(&xs[b][r0 + q][loff], xp[q] + koff);
    };

    float acc[64];
    #pragma unroll
    for (int k = 0; k < 64; ++k) acc[k] = 0.0f;

    // prologue: x(0), x(1) in flight
    issue_x(0, 0);
    issue_x(1, 1);

    #pragma unroll 1
    for (int t = 0; t < NCHUNK - 1; ++t) {
        const int xb = t % 3;
        asm volatile("s_waitcnt vmcnt(4)" ::: "memory");   // x(t) resident
        __builtin_amdgcn_s_barrier();
        __builtin_amdgcn_sched_barrier(0);

        float4 xv[4];
        #pragma unroll
        for (int q = 0; q < 4; ++q)
            xv[q] = *(const float4*)&xs[xb][r0 + q][loff];

        const float* wc = w1e + t * CHUNK + loff;
        #pragma unroll
        for (int g = 0; g < 4; ++g) {
            float4 wv[4];
            #pragma unroll
            for (int oo = 0; oo < 4; ++oo)
                wv[oo] = *(const float4*)(wc + (size_t)(g * 4 + oo) * L1DIM);
            if (g == 3) {
                // all wv of this chunk issued; now the x prefetch is newest
                __builtin_amdgcn_sched_barrier(0);
                if (t + 2 < NCHUNK) issue_x(t + 2, (t + 2) % 3);
                __builtin_amdgcn_sched_barrier(0);
            }
            #pragma unroll
            for (int oo = 0; oo < 4; ++oo) {
                const int o = g * 4 + oo;
                #pragma unroll
                for (int q = 0; q < 4; ++q) {
                    float s = acc[q * 16 + o];
                    s = fmaf(xv[q].x, wv[oo].x, s);
                    s = fmaf(xv[q].y, wv[oo].y, s);
                    s = fmaf(xv[q].z, wv[oo].z, s);
                    s = fmaf(xv[q].w, wv[oo].w, s);
                    acc[q * 16 + o] = s;
                }
            }
        }
        __builtin_amdgcn_s_barrier();   // buffer xb free for reuse next cycle
    }

    // last chunk: drain
    {
        const int t = NCHUNK - 1;
        const int xb = t % 3;
        asm volatile("s_waitcnt vmcnt(0)" ::: "memory");
        __builtin_amdgcn_s_barrier();
        __builtin_amdgcn_sched_barrier(0);
        float4 xv[4];
        #pragma unroll
        for (int q = 0; q < 4; ++q)
            xv[q] = *(const float4*)&xs[xb][r0 + q][loff];
        const float* wc = w1e + t * CHUNK + loff;
        #pragma unroll
        for (int g = 0; g < 4; ++g) {
            float4 wv[4];
            #pragma unroll
            for (int oo = 0; oo < 4; ++oo)
                wv[oo] = *(const float4*)(wc + (size_t)(g * 4 + oo) * L1DIM);
            #pragma unroll
            for (int oo = 0; oo < 4; ++oo) {
                const int o = g * 4 + oo;
                #pragma unroll
                for (int q = 0; q < 4; ++q) {
                    float s = acc[q * 16 + o];
                    s = fmaf(xv[q].x, wv[oo].x, s);
                    s = fmaf(xv[q].y, wv[oo].y, s);
                    s = fmaf(xv[q].z, wv[oo].z, s);
                    s = fmaf(xv[q].w, wv[oo].w, s);
                    acc[q * 16 + o] = s;
                }
            }
        }
    }

    // Reduce-scatter butterfly over 64 lanes: lane l ends with total of idx l.
    #pragma unroll
    for (int s = 0; s < 6; ++s) {
        const int mask = 32 >> s;
        const bool hi = (lane & mask) != 0;
        #pragma unroll
        for (int k = 0; k < 32; ++k) {
            if (k >= mask) break;
            float give = hi ? acc[k] : acc[k + mask];
            float got  = __shfl_xor(give, mask, 64);
            float keep = hi ? acc[k + mask] : acc[k];
            acc[k] = keep + got;
        }
    }

    tot[wid][lane] = acc[0];
    __syncthreads();

    // Epilogue: 16 lanes per row. lane = q*16 + j
    const int q = lane >> 4;
    const int j = lane & 15;
    const int row = rows[q];

    const float* tq = &tot[wid][q * 16];
    float l1x_out = tq[15] + b1[e * 16 + 15];

    float h1v[30];
    #pragma unroll
    for (int i = 0; i < 15; ++i) {
        float t = tq[i] + b1[e * 16 + i];
        float sq = t * t * SQCORR;
        h1v[i]      = fminf(fmaxf(sq, 0.0f), 1.0f);
        h1v[i + 15] = fminf(fmaxf(t,  0.0f), 1.0f);
    }

    float s0 = b2[e * 32 + j];
    float s1 = b2[e * 32 + 16 + j];
    const float* w2e = w2 + (size_t)e * 32 * 30;
    #pragma unroll
    for (int i = 0; i < 30; ++i) {
        s0 = fmaf(h1v[i], w2e[j * 30 + i], s0);
        s1 = fmaf(h1v[i], w2e[(16 + j) * 30 + i], s1);
    }
    s0 = fminf(fmaxf(s0, 0.0f), 1.0f);
    s1 = fminf(fmaxf(s1, 0.0f), 1.0f);

    float p = s0 * w3[e * 32 + j] + s1 * w3[e * 32 + 16 + j];
    #pragma unroll
    for (int m = 8; m >= 1; m >>= 1) p += __shfl_xor(p, m, 64);

    if (j == 0 && row >= 0) out[row] = p + b3[e] + l1x_out;
}

extern "C" void kernel_launch(void* const* d_in, const int* in_sizes, int n_in,
                              void* d_out, int out_size, void* d_ws, size_t ws_size,
                              hipStream_t stream) {
    const float* x       = (const float*)d_in[0];
    const int*   routing = (const int*)d_in[1];
    const float* w1      = (const float*)d_in[2];
    const float* b1      = (const float*)d_in[3];
    const float* w2      = (const float*)d_in[4];
    const float* b2      = (const float*)d_in[5];
    const float* w3      = (const float*)d_in[6];
    const float* b3      = (const float*)d_in[7];
    float* out = (float*)d_out;
    int*   ws  = (int*)d_ws;

    init_k<<<1, 64, 0, stream>>>(ws);
    scatter_k<<<NBLK_SORT, 256, 0, stream>>>(routing, ws);
    moe_main_k<<<NBLK_MAIN, 256, 0, stream>>>(x, ws, w1, b1, w2, b2, w3, b3, out);
}

// Round 6
// 137.836 us; speedup vs baseline: 2.3061x; 1.0073x over previous
//
#include <hip/hip_runtime.h>

// Problem constants
#define NEXP   8
#define L1DIM  3072
#define BATCH  32768
#define SQCORR (127.0f / 128.0f)
#define CHUNK  256                    // K-chunk (floats)
#define NCHUNK (L1DIM / CHUNK)        // 12

// Workspace layout (int units). Fixed per-expert segments: expert e owns
// sorted slots [e*BATCH, e*BATCH + count_e). Cursors padded to 64B lines.
#define CUR_STRIDE  16
#define WS_CURSORS  0                       // [8 * CUR_STRIDE]
#define WS_SORTED   (NEXP * CUR_STRIDE)     // [NEXP*BATCH]
#define NBLK_SORT   (BATCH / 256)           // 128
#define BLK_PER_E   (BATCH / 16)            // 2048
#define NBLK_MAIN   (NEXP * BLK_PER_E)      // 16384 (most early-exit)

__global__ void init_k(int* ws) {
    if (threadIdx.x < NEXP)
        ws[WS_CURSORS + threadIdx.x * CUR_STRIDE] = threadIdx.x * BATCH;
}

// Block-aggregated scatter into fixed expert segments.
__global__ void scatter_k(const int* __restrict__ routing, int* ws) {
    __shared__ int h[NEXP];
    __shared__ int base[NEXP];
    if (threadIdx.x < NEXP) h[threadIdx.x] = 0;
    __syncthreads();
    int i = blockIdx.x * 256 + threadIdx.x;
    int e = routing[i];
    int rank = atomicAdd(&h[e], 1);
    __syncthreads();
    if (threadIdx.x < NEXP)
        base[threadIdx.x] =
            atomicAdd(&ws[WS_CURSORS + threadIdx.x * CUR_STRIDE], h[threadIdx.x]);
    __syncthreads();
    ws[WS_SORTED + base[e] + rank] = i;
}

// async 16B global -> LDS copy (per-lane global src, wave-linear LDS dest)
__device__ __forceinline__ void lds_cp16(void* lds, const void* g) {
    __builtin_amdgcn_global_load_lds(
        (const __attribute__((address_space(1))) void*)g,
        (__attribute__((address_space(3))) void*)lds, 16, 0, 0);
}

// Main fused kernel: 256 threads = 4 FULLY INDEPENDENT waves (no cross-wave
// data flow): wave w stages rows 4w..4w+3 into its own LDS partition, reads
// only that partition, reduces via intra-wave shuffles. NO K-loop barriers —
// waves free-run and destagger, smoothing HBM issue instead of convoying.
//
// Per-wave vmcnt FIFO bookkeeping (gll and global loads share one FIFO):
//   iter t issues: [ds_reads | 16 wv loads | gll x(t+2):4 | FMAs].
//   The compiler's wait before the last wv-consuming FMA is vmcnt(4)
//   (4 newest = the gll), which FIFO-drains everything older — including
//   x(t+1)'s gll issued the previous iter. Hence at the top of iter t+1,
//   outstanding = x(t+2):4 only and x(t+1) is already LDS-resident; the
//   manual vmcnt(4) is a cheap invariant check, never a real stall.
__global__ __launch_bounds__(256, 3) void moe_main_k(
        const float* __restrict__ x, const int* __restrict__ ws,
        const float* __restrict__ w1, const float* __restrict__ b1,
        const float* __restrict__ w2, const float* __restrict__ b2,
        const float* __restrict__ w3, const float* __restrict__ b3,
        float* __restrict__ out) {
    __shared__ float xs[3][16][CHUNK];    // 48 KB; wave w owns rows 4w..4w+3
    __shared__ float tot[4][64];          // wave-private slices

    const int e   = blockIdx.x % NEXP;
    const int b16 = (blockIdx.x / NEXP) * 16;
    const int n   = ws[WS_CURSORS + e * CUR_STRIDE] - e * BATCH;  // count_e
    if (b16 >= n) return;

    const int tid  = threadIdx.x;
    const int wid  = tid >> 6;
    const int lane = tid & 63;
    const int r0   = wid * 4;
    const int loff = lane * 4;

    int rows[4];
    const float* xp[4];
    #pragma unroll
    for (int q = 0; q < 4; ++q) {
        int s = b16 + r0 + q;
        rows[q] = (s < n) ? ws[WS_SORTED + e * BATCH + s] : -1;
        int r = rows[q] < 0 ? 0 : rows[q];
        xp[q] = x + (size_t)r * L1DIM;
    }
    const float* w1e = w1 + (size_t)e * 16 * L1DIM;

    auto issue_x = [&](int t, int b) {
        const int koff = t * CHUNK + loff;
        #pragma unroll
        for (int q = 0; q < 4; ++q)
            lds_cp16(&xs[b][r0 + q][loff], xp[q] + koff);
    };

    float acc[64];
    #pragma unroll
    for (int k = 0; k < 64; ++k) acc[k] = 0.0f;

    // prologue: x(0), x(1) in flight
    issue_x(0, 0);
    issue_x(1, 1);

    #pragma unroll 1
    for (int t = 0; t < NCHUNK; ++t) {
        const int xb = t % 3;
        // x(t) already drained by previous iter's wv waits (see header note);
        // this is a guard, not a stall. Never drains the in-flight prefetch.
        asm volatile("s_waitcnt vmcnt(4)" ::: "memory");

        float4 xv[4];
        #pragma unroll
        for (int q = 0; q < 4; ++q)
            xv[q] = *(const float4*)&xs[xb][r0 + q][loff];

        // all 16 w1 vectors of this chunk: compiler free to hoist/cluster
        // them (64 VGPRs) so L2 latency is hidden under the FMA block.
        const float* wc = w1e + t * CHUNK + loff;
        float4 wv[16];
        #pragma unroll
        for (int o = 0; o < 16; ++o)
            wv[o] = *(const float4*)(wc + (size_t)o * L1DIM);

        // pin the x prefetch AFTER all wv loads (keeps gll newest in FIFO)
        __builtin_amdgcn_sched_barrier(0);
        if (t + 2 < NCHUNK) issue_x(t + 2, (t + 2) % 3);
        __builtin_amdgcn_sched_barrier(0);

        #pragma unroll
        for (int o = 0; o < 16; ++o) {
            #pragma unroll
            for (int q = 0; q < 4; ++q) {
                float s = acc[q * 16 + o];
                s = fmaf(xv[q].x, wv[o].x, s);
                s = fmaf(xv[q].y, wv[o].y, s);
                s = fmaf(xv[q].z, wv[o].z, s);
                s = fmaf(xv[q].w, wv[o].w, s);
                acc[q * 16 + o] = s;
            }
        }
    }

    // Reduce-scatter butterfly over 64 lanes: lane l ends with total of idx l.
    #pragma unroll
    for (int s = 0; s < 6; ++s) {
        const int mask = 32 >> s;
        const bool hi = (lane & mask) != 0;
        #pragma unroll
        for (int k = 0; k < 32; ++k) {
            if (k >= mask) break;
            float give = hi ? acc[k] : acc[k + mask];
            float got  = __shfl_xor(give, mask, 64);
            float keep = hi ? acc[k + mask] : acc[k];
            acc[k] = keep + got;
        }
    }

    tot[wid][lane] = acc[0];
    __syncthreads();   // single barrier: orders the wave-private LDS totals

    // Epilogue: 16 lanes per row. lane = q*16 + j
    const int q = lane >> 4;
    const int j = lane & 15;
    const int row = rows[q];

    const float* tq = &tot[wid][q * 16];
    float l1x_out = tq[15] + b1[e * 16 + 15];

    float h1v[30];
    #pragma unroll
    for (int i = 0; i < 15; ++i) {
        float t = tq[i] + b1[e * 16 + i];
        float sq = t * t * SQCORR;
        h1v[i]      = fminf(fmaxf(sq, 0.0f), 1.0f);
        h1v[i + 15] = fminf(fmaxf(t,  0.0f), 1.0f);
    }

    float s0 = b2[e * 32 + j];
    float s1 = b2[e * 32 + 16 + j];
    const float* w2e = w2 + (size_t)e * 32 * 30;
    #pragma unroll
    for (int i = 0; i < 30; ++i) {
        s0 = fmaf(h1v[i], w2e[j * 30 + i], s0);
        s1 = fmaf(h1v[i], w2e[(16 + j) * 30 + i], s1);
    }
    s0 = fminf(fmaxf(s0, 0.0f), 1.0f);
    s1 = fminf(fmaxf(s1, 0.0f), 1.0f);

    float p = s0 * w3[e * 32 + j] + s1 * w3[e * 32 + 16 + j];
    #pragma unroll
    for (int m = 8; m >= 1; m >>= 1) p += __shfl_xor(p, m, 64);

    if (j == 0 && row >= 0) out[row] = p + b3[e] + l1x_out;
}

extern "C" void kernel_launch(void* const* d_in, const int* in_sizes, int n_in,
                              void* d_out, int out_size, void* d_ws, size_t ws_size,
                              hipStream_t stream) {
    const float* x       = (const float*)d_in[0];
    const int*   routing = (const int*)d_in[1];
    const float* w1      = (const float*)d_in[2];
    const float* b1      = (const float*)d_in[3];
    const float* w2      = (const float*)d_in[4];
    const float* b2      = (const float*)d_in[5];
    const float* w3      = (const float*)d_in[6];
    const float* b3      = (const float*)d_in[7];
    float* out = (float*)d_out;
    int*   ws  = (int*)d_ws;

    init_k<<<1, 64, 0, stream>>>(ws);
    scatter_k<<<NBLK_SORT, 256, 0, stream>>>(routing, ws);
    moe_main_k<<<NBLK_MAIN, 256, 0, stream>>>(x, ws, w1, b1, w2, b2, w3, b3, out);
}